// Round 2
// baseline (263.453 us; speedup 1.0000x reference)
//
#include <hip/hip_runtime.h>
#include <stdint.h>

#define V3 110592        // 48*48*48
#define PLANE 2304       // 48*48
#define NI 32
#define NO 64
#define KTOT 320         // NI*10 shells
#define PSTR 24          // padded LDS plane row stride (floats); 2-way bank alias only (free)
#define PLSZ (20*PSTR)
#define DCH 6            // d-outputs per block
#define NPL 10           // staged planes = DCH+4

typedef unsigned short ushort_t;
typedef __attribute__((ext_vector_type(8))) short short8v;
typedef __attribute__((ext_vector_type(4))) float float4v;

__device__ __forceinline__ uint32_t f2bf1(float f) {
  uint32_t u = __float_as_uint(f);
  u += 0x7FFFu + ((u >> 16) & 1u);   // RNE
  return u >> 16;
}
__device__ __forceinline__ uint32_t pack2(float a, float b) {
  return f2bf1(a) | (f2bf1(b) << 16);
}

// ---------- prep: Abf[m][k] = bf16(Y0 * weight[m*320+k]) ----------
__global__ void prep_kernel(const float* __restrict__ w, ushort_t* __restrict__ Abf) {
  int idx = blockIdx.x * 256 + threadIdx.x;
  if (idx < NO * KTOT) Abf[idx] = (ushort_t)f2bf1(0.28209479177387814f * w[idx]);
}

// ---------- pass 1: shell sums, S in blocked layout [g=k/8][n][k%8] (bf16) ----------
// block: 16x16 (h,w) sites x DCH d-outputs x 4 input channels (i-group)
__global__ __launch_bounds__(256) void shell_kernel(const float* __restrict__ xb,
                                                    ushort_t* __restrict__ S,
                                                    int dd, int Nch) {
  __shared__ float pl[NPL][PLSZ];
  const int tid = threadIdx.x;
  const int hh = tid >> 4, ww = tid & 15;
  const int h0 = (blockIdx.x / 3) * 16, w0 = (blockIdx.x % 3) * 16;
  const int d0 = dd + blockIdx.y * DCH;
  const int ig = blockIdx.z;

  // staging site A: s=tid, site B: s=tid+256 (valid tid<144); 400 sites of 20x20
  const int lh1 = tid / 20, lw1 = tid % 20;
  const int s2 = tid + 256;
  const int lh2 = s2 / 20, lw2 = s2 % 20;
  const int gh1 = h0 - 2 + lh1, gw1 = w0 - 2 + lw1;
  const int gh2 = h0 - 2 + lh2, gw2 = w0 - 2 + lw2;
  const bool ok1 = (gh1 >= 0 && gh1 < 48 && gw1 >= 0 && gw1 < 48);
  const bool ok2 = (tid < 144) && (gh2 >= 0 && gh2 < 48 && gw2 >= 0 && gw2 < 48);
  const int a1 = lh1 * PSTR + lw1, a2 = lh2 * PSTR + lw2;
  const int o1 = gh1 * 48 + gw1, o2 = gh2 * 48 + gw2;
  const int site = (h0 + hh) * 48 + (w0 + ww);
  uint32_t* Sd = (uint32_t*)S;

#pragma unroll
  for (int ii = 0; ii < 4; ++ii) {
    const int i = ig * 4 + ii;
    const float* xi = xb + (size_t)i * V3;

    __syncthreads();   // previous iteration's readers done
#pragma unroll
    for (int j = 0; j < NPL; ++j) {
      int gd = d0 - 2 + j;
      float v1 = 0.f, v2 = 0.f;
      if (gd >= 0 && gd < 48) {
        const float* xp = xi + (size_t)gd * PLANE;
        if (ok1) v1 = xp[o1];
        if (ok2) v2 = xp[o2];
      }
      pl[j][a1] = v1;
      if (tid < 144) pl[j][a2] = v2;
    }
    __syncthreads();

    // per-plane 2D shell sums: B[q][j], q = dx^2+dy^2 class in {0,1,2,4,5,8}
    float B[6][NPL];
#pragma unroll
    for (int j = 0; j < NPL; ++j) {
      float a0[5], s1[5], s4[5];
#pragma unroll
      for (int dy = 0; dy < 5; ++dy) {
        const float* row = &pl[j][(hh + dy) * PSTR + ww];
        float r0 = row[0], r1 = row[1], r2 = row[2], r3 = row[3], r4 = row[4];
        a0[dy] = r2; s1[dy] = r1 + r3; s4[dy] = r0 + r4;
      }
      B[0][j] = a0[2];
      B[1][j] = s1[2] + a0[1] + a0[3];
      B[2][j] = s1[1] + s1[3];
      B[3][j] = s4[2] + a0[0] + a0[4];
      B[4][j] = s4[1] + s4[3] + s1[0] + s1[4];
      B[5][j] = s4[0] + s4[4];
    }

    // 3D shells r^2 in {0,1,2,3,4,5,6,8,9,12}; output d = d0+t uses planes t..t+4
    // store pieces: k0 = i*10; within i-group of 4, k-range 40*ig..40*ig+39 is
    // 8-aligned, so all partial groups are completed by this same block (same L2).
    const int goff = (10 * ii) >> 3;          // 0,1,2,3
    const int off0 = ((10 * ii) & 7) >> 1;    // 0,1,2,3
    const int f = 4 - off0;                   // dwords in first piece
    const size_t gbase = (size_t)(ig * 5 + goff) * Nch;
#pragma unroll
    for (int t = 0; t < DCH; ++t) {
      float Sv[10];
      Sv[0] = B[0][t+2];
      Sv[1] = B[1][t+2] + B[0][t+1] + B[0][t+3];
      Sv[2] = B[2][t+2] + B[1][t+1] + B[1][t+3];
      Sv[3] = B[2][t+1] + B[2][t+3];
      Sv[4] = B[3][t+2] + B[0][t]   + B[0][t+4];
      Sv[5] = B[4][t+2] + B[3][t+1] + B[3][t+3] + B[1][t] + B[1][t+4];
      Sv[6] = B[4][t+1] + B[4][t+3] + B[2][t]   + B[2][t+4];
      Sv[7] = B[5][t+2] + B[3][t]   + B[3][t+4];
      Sv[8] = B[5][t+1] + B[5][t+3] + B[4][t]   + B[4][t+4];
      Sv[9] = B[5][t]   + B[5][t+4];

      uint32_t r[5];
      r[0] = pack2(Sv[0], Sv[1]); r[1] = pack2(Sv[2], Sv[3]);
      r[2] = pack2(Sv[4], Sv[5]); r[3] = pack2(Sv[6], Sv[7]);
      r[4] = pack2(Sv[8], Sv[9]);

      size_t n = (size_t)(d0 + t - dd) * PLANE + site;
      uint32_t* p1 = Sd + (gbase + n) * 4 + off0;
#pragma unroll
      for (int u = 0; u < f; ++u) p1[u] = r[u];
      if (f < 5) {
        uint32_t* p2 = Sd + (gbase + (size_t)Nch + n) * 4;
#pragma unroll
        for (int u = 0; u < 5 - f; ++u) p2[u] = r[f + u];
      }
    }
  }
}

// ---------- pass 2: out[m][v] = sum_k A[m][k]*S[k][n] + bias[m] ----------
__global__ __launch_bounds__(256) void gemm_kernel(const ushort_t* __restrict__ S,
                                                   const ushort_t* __restrict__ Abf,
                                                   const float* __restrict__ bias,
                                                   float* __restrict__ outb,
                                                   int dd, int Nch) {
  const int tid = threadIdx.x;
  const int lane = tid & 63, wi = tid >> 6;
  const int quad = lane >> 4, m15 = lane & 15;
  const int n_base = blockIdx.x * 128 + wi * 32;

  float4v acc[4][2];
#pragma unroll
  for (int mt = 0; mt < 4; ++mt)
#pragma unroll
    for (int nt = 0; nt < 2; ++nt) acc[mt][nt] = (float4v){0.f, 0.f, 0.f, 0.f};

#pragma unroll
  for (int ks = 0; ks < 10; ++ks) {
    short8v af[4];
#pragma unroll
    for (int mt = 0; mt < 4; ++mt)   // A[m][ks*32+quad*8 ..+7], 16B, L2-hot
      af[mt] = *(const short8v*)&Abf[(mt * 16 + m15) * KTOT + ks * 32 + quad * 8];
    short8v bfr[2];
#pragma unroll
    for (int nt = 0; nt < 2; ++nt) { // blocked S: one coalesced 16B load per lane
      size_t n = (size_t)(n_base + nt * 16 + m15);
      bfr[nt] = *(const short8v*)&S[((size_t)(ks * 4 + quad) * Nch + n) * 8];
    }
#pragma unroll
    for (int mt = 0; mt < 4; ++mt)
#pragma unroll
      for (int nt = 0; nt < 2; ++nt)
        acc[mt][nt] = __builtin_amdgcn_mfma_f32_16x16x32_bf16(af[mt], bfr[nt], acc[mt][nt], 0, 0, 0);
  }

  // C/D: col(n)=lane&15, row(m)=quad*4+reg
  const int v_col = dd * PLANE + n_base + m15;
#pragma unroll
  for (int mt = 0; mt < 4; ++mt) {
#pragma unroll
    for (int r = 0; r < 4; ++r) {
      int m = mt * 16 + quad * 4 + r;
      float bv = bias[m];
      float* op = outb + (size_t)m * V3 + v_col;
#pragma unroll
      for (int nt = 0; nt < 2; ++nt)
        op[nt * 16] = acc[mt][nt][r] + bv;
    }
  }
}

extern "C" void kernel_launch(void* const* d_in, const int* in_sizes, int n_in,
                              void* d_out, int out_size, void* d_ws, size_t ws_size,
                              hipStream_t stream) {
  const float* x    = (const float*)d_in[0];   // [2,32,1,48,48,48]
  const float* w    = (const float*)d_in[1];   // [64,32,1,1,1,10]
  const float* bias = (const float*)d_in[2];   // [64]
  float* out = (float*)d_out;                  // [2,64,1,48,48,48]

  ushort_t* Abf = (ushort_t*)d_ws;
  ushort_t* S   = (ushort_t*)((char*)d_ws + 65536);
  size_t avail = (ws_size > 65536) ? ws_size - 65536 : 0;
  const size_t SBYTES = (size_t)KTOT * V3 * 2;  // 70.8 MB for full batch
  int dlen = 48;
  if (avail < SBYTES) dlen = (avail >= SBYTES / 2) ? 24 : 12;

  prep_kernel<<<80, 256, 0, stream>>>(w, Abf);
  for (int b = 0; b < 2; ++b) {
    const float* xb = x + (size_t)b * NI * V3;
    float* outb = out + (size_t)b * NO * V3;
    for (int dd = 0; dd < 48; dd += dlen) {
      int Nch = dlen * PLANE;
      dim3 g1(9, dlen / DCH, 8);
      shell_kernel<<<g1, 256, 0, stream>>>(xb, S, dd, Nch);
      gemm_kernel<<<Nch / 128, 256, 0, stream>>>(S, Abf, bias, outb, dd, Nch);
    }
  }
}

// Round 3
// 226.560 us; speedup vs baseline: 1.1628x; 1.1628x over previous
//
#include <hip/hip_runtime.h>
#include <stdint.h>

#define V3 110592        // 48*48*48
#define PLANE 2304       // 48*48
#define NO 64
#define KW 192           // K per dz-shift = 32 i * 6 q-classes
#define AWSTR 200        // LDS A row stride (shorts): even 8-way quad-bank spread

typedef unsigned short ushort_t;
typedef __attribute__((ext_vector_type(8))) short short8v;
typedef __attribute__((ext_vector_type(4))) float float4v;

__device__ __forceinline__ uint32_t f2bf1(float f) {
  uint32_t u = __float_as_uint(f);
  u += 0x7FFFu + ((u >> 16) & 1u);   // RNE
  return u >> 16;
}
__device__ __forceinline__ uint32_t pack2(float a, float b) {
  return f2bf1(a) | (f2bf1(b) << 16);
}

// ---------- prep: W2[dz][m][k'=i*6+qi] = bf16(Y0 * w[m,i,p(q+dz^2)]) ----------
__global__ void prep_kernel(const float* __restrict__ w, ushort_t* __restrict__ W2) {
  int idx = blockIdx.x * 256 + threadIdx.x;     // 5*64*192 = 61440
  if (idx >= 5 * NO * KW) return;
  int k = idx % KW;
  int m = (idx / KW) % NO;
  int dzi = idx / (KW * NO);
  int i = k / 6, qi = k % 6;
  const int Q[6] = {0, 1, 2, 4, 5, 8};
  const int pidx[13] = {0, 1, 2, 3, 4, 5, 6, 0, 7, 8, 0, 0, 9};  // r2 -> shell index
  int dz = dzi - 2;
  int p = pidx[Q[qi] + dz * dz];
  W2[idx] = (ushort_t)f2bf1(0.28209479177387814f * w[(m * 32 + i) * 10 + p]);
}

// ---------- pass 1: per-plane 2D class sums, Bq blocked [g=k'/8][n][8] bf16 ----------
// block: 192 thr; tile = full 48 w x 16 h x 1 d-plane x 4 input channels
__global__ __launch_bounds__(192) void bq_kernel(const float* __restrict__ xb,
                                                 ushort_t* __restrict__ Bq) {
  __shared__ float pl[20 * 53];
  const int tid = threadIdx.x;
  const int hs = blockIdx.x % 3, d = blockIdx.x / 3;   // gridDim.x = 144
  const int ig = blockIdx.y;                           // 0..7 (i-group of 4)
  const int h0 = hs * 16;
  const int ww = tid % 48, ty = tid / 48;              // ty 0..3, 4 h-sites each

  uint32_t rg[4][4][3];                                // [ii][site][3 dwords of 6 bf16]
#pragma unroll
  for (int ii = 0; ii < 4; ++ii) {
    const int i = ig * 4 + ii;
    const float* xp = xb + ((size_t)i * 48 + d) * PLANE;
    __syncthreads();
    for (int s = tid; s < 1040; s += 192) {            // stage 52x20 halo tile
      int r = s / 52, c = s % 52;
      int gh = h0 - 2 + r, gw = c - 2;
      float v = 0.f;
      if (gh >= 0 && gh < 48 && gw >= 0 && gw < 48) v = xp[gh * 48 + gw];
      pl[r * 53 + c] = v;
    }
    __syncthreads();

    float a0r[8], s1r[8], s4r[8];                      // row sums, 8 rows per thread
#pragma unroll
    for (int dy = 0; dy < 8; ++dy) {
      const float* row = &pl[(ty * 4 + dy) * 53 + ww];
      float r0 = row[0], r1 = row[1], r2 = row[2], r3 = row[3], r4 = row[4];
      a0r[dy] = r2; s1r[dy] = r1 + r3; s4r[dy] = r0 + r4;
    }
#pragma unroll
    for (int j = 0; j < 4; ++j) {                      // 4 h-sites
      float B0 = a0r[j + 2];
      float B1 = s1r[j + 2] + a0r[j + 1] + a0r[j + 3];
      float B2 = s1r[j + 1] + s1r[j + 3];
      float B3 = s4r[j + 2] + a0r[j] + a0r[j + 4];
      float B4 = s4r[j + 1] + s4r[j + 3] + s1r[j] + s1r[j + 4];
      float B5 = s4r[j] + s4r[j + 4];
      rg[ii][j][0] = pack2(B0, B1);
      rg[ii][j][1] = pack2(B2, B3);
      rg[ii][j][2] = pack2(B4, B5);
    }
  }
  // dense 48B per site (k' = 24*ig .. +23 -> groups 3ig..3ig+2), 3 x dwordx4
#pragma unroll
  for (int j = 0; j < 4; ++j) {
    size_t n = (size_t)d * PLANE + (size_t)(h0 + ty * 4 + j) * 48 + ww;
    uint4 c0 = {rg[0][j][0], rg[0][j][1], rg[0][j][2], rg[1][j][0]};
    uint4 c1 = {rg[1][j][1], rg[1][j][2], rg[2][j][0], rg[2][j][1]};
    uint4 c2 = {rg[2][j][2], rg[3][j][0], rg[3][j][1], rg[3][j][2]};
    *(uint4*)(Bq + ((size_t)(3 * ig + 0) * V3 + n) * 8) = c0;
    *(uint4*)(Bq + ((size_t)(3 * ig + 1) * V3 + n) * 8) = c1;
    *(uint4*)(Bq + ((size_t)(3 * ig + 2) * V3 + n) * 8) = c2;
  }
}

// ---------- pass 2: out[m][d,hw] = sum_dz sum_k W2[dz][m][k] * Bq[k][(d+dz),hw] ----------
__global__ __launch_bounds__(256) void gemm_kernel(const ushort_t* __restrict__ Bq,
                                                   const ushort_t* __restrict__ W2,
                                                   const float* __restrict__ bias,
                                                   float* __restrict__ outb) {
  __shared__ ushort_t Aw[NO * AWSTR];                  // 25.6 KB
  const int tid = threadIdx.x;
  const int lane = tid & 63, wi = tid >> 6;
  const int quad = lane >> 4, m15 = lane & 15;
  const int tile = blockIdx.x;                         // 0..17 (n-tile in plane)
  const int d = blockIdx.y;                            // 0..47

  float4v acc[4][2];
#pragma unroll
  for (int mt = 0; mt < 4; ++mt)
#pragma unroll
    for (int nt = 0; nt < 2; ++nt) acc[mt][nt] = (float4v){0.f, 0.f, 0.f, 0.f};

  for (int dzi = 0; dzi < 5; ++dzi) {
    int dp = d + dzi - 2;
    if ((unsigned)dp >= 48u) continue;                 // uniform per block
    __syncthreads();
    {                                                  // stage A dz-slice into LDS
      const uint32_t* Wd = (const uint32_t*)(W2 + dzi * NO * KW);
      uint32_t* Awd = (uint32_t*)Aw;
      for (int e = tid; e < NO * KW / 2; e += 256) {   // 6144 dwords
        int row = e / 96, col = e % 96;
        Awd[row * 100 + col] = Wd[e];
      }
    }
    __syncthreads();
    for (int ks = 0; ks < 6; ++ks) {
      short8v af[4];
#pragma unroll
      for (int mt = 0; mt < 4; ++mt)
        af[mt] = *(const short8v*)&Aw[(mt * 16 + m15) * AWSTR + ks * 32 + quad * 8];
      short8v bfr[2];
#pragma unroll
      for (int nt = 0; nt < 2; ++nt) {
        size_t n = (size_t)dp * PLANE + tile * 128 + wi * 32 + nt * 16 + m15;
        bfr[nt] = *(const short8v*)&Bq[((size_t)(ks * 4 + quad) * V3 + n) * 8];
      }
#pragma unroll
      for (int mt = 0; mt < 4; ++mt)
#pragma unroll
        for (int nt = 0; nt < 2; ++nt)
          acc[mt][nt] = __builtin_amdgcn_mfma_f32_16x16x32_bf16(af[mt], bfr[nt], acc[mt][nt], 0, 0, 0);
    }
  }

  // C/D: col(n)=lane&15, row(m)=quad*4+reg
  const int vb = d * PLANE + tile * 128 + wi * 32 + m15;
#pragma unroll
  for (int mt = 0; mt < 4; ++mt) {
#pragma unroll
    for (int r = 0; r < 4; ++r) {
      int m = mt * 16 + quad * 4 + r;
      float bv = bias[m];
      float* op = outb + (size_t)m * V3 + vb;
#pragma unroll
      for (int nt = 0; nt < 2; ++nt)
        op[nt * 16] = acc[mt][nt][r] + bv;
    }
  }
}

extern "C" void kernel_launch(void* const* d_in, const int* in_sizes, int n_in,
                              void* d_out, int out_size, void* d_ws, size_t ws_size,
                              hipStream_t stream) {
  const float* x    = (const float*)d_in[0];   // [2,32,1,48,48,48]
  const float* w    = (const float*)d_in[1];   // [64,32,1,1,1,10]
  const float* bias = (const float*)d_in[2];   // [64]
  float* out = (float*)d_out;                  // [2,64,1,48,48,48]

  ushort_t* W2 = (ushort_t*)d_ws;                          // 122880 B
  ushort_t* Bq = (ushort_t*)((char*)d_ws + 131072);        // 42.5 MB (per batch)

  prep_kernel<<<(5 * NO * KW + 255) / 256, 256, 0, stream>>>(w, W2);
  for (int b = 0; b < 2; ++b) {
    const float* xb = x + (size_t)b * 32 * V3;
    float* outb = out + (size_t)b * 64 * V3;
    bq_kernel<<<dim3(144, 8), 192, 0, stream>>>(xb, Bq);
    gemm_kernel<<<dim3(18, 48), 256, 0, stream>>>(Bq, W2, bias, outb);
  }
}

// Round 4
// 218.557 us; speedup vs baseline: 1.2054x; 1.0366x over previous
//
#include <hip/hip_runtime.h>
#include <stdint.h>

#define V3 110592        // 48*48*48
#define PLANE 2304       // 48*48
#define NO 64
#define KW 192           // K per dz-slice = 32 i * 6 q-classes

typedef unsigned short ushort_t;
typedef __attribute__((ext_vector_type(8))) short short8v;
typedef __attribute__((ext_vector_type(4))) float float4v;

__device__ __forceinline__ uint32_t f2bf1(float f) {
  uint32_t u = __float_as_uint(f);
  u += 0x7FFFu + ((u >> 16) & 1u);   // RNE
  return u >> 16;
}
__device__ __forceinline__ uint32_t pack2(float a, float b) {
  return f2bf1(a) | (f2bf1(b) << 16);
}

// ---------- prep: W3[sl][m][k'=i*6+qi] = bf16(Y0 * w[m,i,p(Q[qi]+sl^2)]), sl=|dz| ----------
__global__ void prep_kernel(const float* __restrict__ w, ushort_t* __restrict__ W3) {
  int idx = blockIdx.x * 256 + threadIdx.x;     // 3*64*192 = 36864
  if (idx >= 3 * NO * KW) return;
  int k = idx % KW;
  int m = (idx / KW) % NO;
  int sl = idx / (KW * NO);
  int i = k / 6, qi = k % 6;
  const int Q[6] = {0, 1, 2, 4, 5, 8};
  const int dd2[3] = {0, 1, 4};
  const int pidx[13] = {0, 1, 2, 3, 4, 5, 6, 0, 7, 8, 0, 0, 9};  // r2 -> shell index
  int p = pidx[Q[qi] + dd2[sl]];
  W3[idx] = (ushort_t)f2bf1(0.28209479177387814f * w[(m * 32 + i) * 10 + p]);
}

// ---------- pass 1: per-plane 2D class sums, Bq blocked [g=k'/8][n][8] bf16 ----------
// block: 192 thr, tile = 48w x 16h x 1 plane x 4 i; ONE barrier pair.
__global__ __launch_bounds__(192) void bq_kernel(const float* __restrict__ x,
                                                 ushort_t* __restrict__ Bq) {
  __shared__ float pl[4][20 * 53];
  const int tid = threadIdx.x;
  const int hs = blockIdx.x % 3, d = blockIdx.x / 3;   // gridDim.x = 144
  const int ig = blockIdx.y;                           // i-group of 4
  const int h0 = hs * 16;
  const float* xb = x + (size_t)blockIdx.z * 32 * V3;
  ushort_t* Bqb = Bq + (size_t)blockIdx.z * 24 * V3 * 8;

  for (int s = tid; s < 4 * 1040; s += 192) {          // stage 4 x (20x52) halo tiles
    int ii = s / 1040, rem = s - ii * 1040;
    int r = rem / 52, c = rem % 52;
    int gh = h0 - 2 + r, gw = c - 2;
    float v = 0.f;
    if (gh >= 0 && gh < 48 && gw >= 0 && gw < 48)
      v = xb[((size_t)(ig * 4 + ii) * 48 + d) * PLANE + gh * 48 + gw];
    pl[ii][r * 53 + c] = v;
  }
  __syncthreads();

  const int ww = tid % 48, ty = tid / 48;              // ty 0..3, 4 h-sites each
  uint32_t rg[4][4][3];
#pragma unroll
  for (int ii = 0; ii < 4; ++ii) {
    float a0r[8], s1r[8], s4r[8];
#pragma unroll
    for (int dy = 0; dy < 8; ++dy) {
      const float* row = &pl[ii][(ty * 4 + dy) * 53 + ww];
      float r0 = row[0], r1 = row[1], r2 = row[2], r3 = row[3], r4 = row[4];
      a0r[dy] = r2; s1r[dy] = r1 + r3; s4r[dy] = r0 + r4;
    }
#pragma unroll
    for (int j = 0; j < 4; ++j) {
      float B0 = a0r[j + 2];
      float B1 = s1r[j + 2] + a0r[j + 1] + a0r[j + 3];
      float B2 = s1r[j + 1] + s1r[j + 3];
      float B3 = s4r[j + 2] + a0r[j] + a0r[j + 4];
      float B4 = s4r[j + 1] + s4r[j + 3] + s1r[j] + s1r[j + 4];
      float B5 = s4r[j] + s4r[j + 4];
      rg[ii][j][0] = pack2(B0, B1);
      rg[ii][j][1] = pack2(B2, B3);
      rg[ii][j][2] = pack2(B4, B5);
    }
  }
  // dense 48 B per site (k' = 24*ig..+23 -> groups 3ig..3ig+2), 3 x dwordx4
#pragma unroll
  for (int j = 0; j < 4; ++j) {
    size_t n = (size_t)d * PLANE + (size_t)(h0 + ty * 4 + j) * 48 + ww;
    uint4 c0 = {rg[0][j][0], rg[0][j][1], rg[0][j][2], rg[1][j][0]};
    uint4 c1 = {rg[1][j][1], rg[1][j][2], rg[2][j][0], rg[2][j][1]};
    uint4 c2 = {rg[2][j][2], rg[3][j][0], rg[3][j][1], rg[3][j][2]};
    *(uint4*)(Bqb + ((size_t)(3 * ig + 0) * V3 + n) * 8) = c0;
    *(uint4*)(Bqb + ((size_t)(3 * ig + 1) * V3 + n) * 8) = c1;
    *(uint4*)(Bqb + ((size_t)(3 * ig + 2) * V3 + n) * 8) = c2;
  }
}

// ---------- pass 2: out[m][d,n] = sum_dz sum_k W3[|dz|][m][k] * Bq[k][(d+dz),n] ----------
// no LDS, no barriers; D=2 d-outputs per block; n-tile 64 (4 waves x 16n)
__global__ __launch_bounds__(256) void gemm_kernel(const ushort_t* __restrict__ Bq,
                                                   const ushort_t* __restrict__ W3,
                                                   const float* __restrict__ bias,
                                                   float* __restrict__ out) {
  const int tid = threadIdx.x;
  const int lane = tid & 63, wi = tid >> 6;
  const int quad = lane >> 4, m15 = lane & 15;
  const int d0 = blockIdx.y * 2;
  const ushort_t* Bqb = Bq + (size_t)blockIdx.z * 24 * V3 * 8;
  float* outb = out + (size_t)blockIdx.z * NO * V3;
  const int npl = blockIdx.x * 64 + wi * 16 + m15;     // site within plane

  float4v acc[4][2];
#pragma unroll
  for (int mt = 0; mt < 4; ++mt)
#pragma unroll
    for (int t = 0; t < 2; ++t) acc[mt][t] = (float4v){0.f, 0.f, 0.f, 0.f};

  const short8v zf = (short8v){0, 0, 0, 0, 0, 0, 0, 0};
#pragma unroll
  for (int ks = 0; ks < 6; ++ks) {
    short8v af[4][3];                                  // [mt][slice=|dz|]
#pragma unroll
    for (int sl = 0; sl < 3; ++sl)
#pragma unroll
      for (int mt = 0; mt < 4; ++mt)
        af[mt][sl] = *(const short8v*)&W3[(size_t)(sl * NO + mt * 16 + m15) * KW + ks * 32 + quad * 8];

    short8v bf[6];                                     // planes d0-2 .. d0+3
#pragma unroll
    for (int p = 0; p < 6; ++p) {
      int dp = d0 - 2 + p;
      if (dp >= 0 && dp < 48)                          // wave-uniform
        bf[p] = *(const short8v*)&Bqb[((size_t)(ks * 4 + quad) * V3 + (size_t)dp * PLANE + npl) * 8];
      else
        bf[p] = zf;                                    // zero B -> MFMA no-op
    }

    // slice map for dzi 0..4 (dz=-2..2): |dz| = 2,1,0,1,2
#pragma unroll
    for (int t = 0; t < 2; ++t) {
#pragma unroll
      for (int dzi = 0; dzi < 5; ++dzi) {
        const int sl = (dzi == 2) ? 0 : ((dzi == 1 || dzi == 3) ? 1 : 2);
        const int p = t + dzi;
#pragma unroll
        for (int mt = 0; mt < 4; ++mt)
          acc[mt][t] = __builtin_amdgcn_mfma_f32_16x16x32_bf16(af[mt][sl], bf[p], acc[mt][t], 0, 0, 0);
      }
    }
  }

  // C/D: col(n)=lane&15, row(m)=quad*4+reg
#pragma unroll
  for (int t = 0; t < 2; ++t) {
    const int vb = (d0 + t) * PLANE + blockIdx.x * 64 + wi * 16 + m15;
#pragma unroll
    for (int mt = 0; mt < 4; ++mt) {
#pragma unroll
      for (int r = 0; r < 4; ++r) {
        int m = mt * 16 + quad * 4 + r;
        outb[(size_t)m * V3 + vb] = acc[mt][t][r] + bias[m];
      }
    }
  }
}

extern "C" void kernel_launch(void* const* d_in, const int* in_sizes, int n_in,
                              void* d_out, int out_size, void* d_ws, size_t ws_size,
                              hipStream_t stream) {
  const float* x    = (const float*)d_in[0];   // [2,32,1,48,48,48]
  const float* w    = (const float*)d_in[1];   // [64,32,1,1,1,10]
  const float* bias = (const float*)d_in[2];   // [64]
  float* out = (float*)d_out;                  // [2,64,1,48,48,48]

  ushort_t* W3 = (ushort_t*)d_ws;                          // 73728 B
  ushort_t* Bq = (ushort_t*)((char*)d_ws + 131072);
  const size_t SB = (size_t)24 * V3 * 8 * 2;               // 42.5 MB per batch
  const bool both = (ws_size >= 131072 + 2 * SB);

  prep_kernel<<<144, 256, 0, stream>>>(w, W3);
  if (both) {
    bq_kernel<<<dim3(144, 8, 2), 192, 0, stream>>>(x, Bq);
    gemm_kernel<<<dim3(36, 24, 2), 256, 0, stream>>>(Bq, W3, bias, out);
  } else {
    for (int b = 0; b < 2; ++b) {
      bq_kernel<<<dim3(144, 8, 1), 192, 0, stream>>>(x + (size_t)b * 32 * V3, Bq);
      gemm_kernel<<<dim3(36, 24, 1), 256, 0, stream>>>(Bq, W3, bias, out + (size_t)b * NO * V3);
    }
  }
}

// Round 5
// 192.104 us; speedup vs baseline: 1.3714x; 1.1377x over previous
//
#include <hip/hip_runtime.h>
#include <stdint.h>

#define V3 110592        // 48*48*48
#define PLANE 2304       // 48*48
#define NO 64

typedef unsigned short ushort_t;
typedef __attribute__((ext_vector_type(8))) short short8v;
typedef __attribute__((ext_vector_type(4))) float float4v;

__device__ __forceinline__ uint32_t f2bf1(float f) {
  uint32_t u = __float_as_uint(f);
  u += 0x7FFFu + ((u >> 16) & 1u);   // RNE
  return u >> 16;
}
__device__ __forceinline__ uint32_t pack2(float a, float b) {
  return f2bf1(a) | (f2bf1(b) << 16);
}

// ---------- prep: Afr[g=kk/8][m][8] bf16, kk = dzi*192 + i*6 + qi ----------
__global__ void prep_kernel(const float* __restrict__ w, ushort_t* __restrict__ Afr) {
  int idx = blockIdx.x * 256 + threadIdx.x;     // 120*64*8 = 61440
  if (idx >= 120 * 64 * 8) return;
  int r = idx & 7, m = (idx >> 3) & 63, g = idx >> 9;
  int kk = g * 8 + r;
  int dzi = kk / 192, k2 = kk % 192;
  int i = k2 / 6, qi = k2 % 6;
  const int Q[6] = {0, 1, 2, 4, 5, 8};
  const int pidx[13] = {0, 1, 2, 3, 4, 5, 6, 0, 7, 8, 0, 0, 9};  // r2 -> shell
  int dz = dzi - 2;
  int p = pidx[Q[qi] + dz * dz];
  Afr[idx] = (ushort_t)f2bf1(0.28209479177387814f * w[(m * 32 + i) * 10 + p]);
}

// ---------- pass 1: per-plane 2D class sums; NO LDS, NO barriers ----------
// wave-autonomous: lanes = w (52 active incl. halo), shfl for dx, rolling regs
// for dy. Bq layout [G = d*24 + g][n][8] bf16, G-groups of 8 k' (k' = i*6+qi).
__global__ __launch_bounds__(256) void bq_kernel(const float* __restrict__ x,
                                                 ushort_t* __restrict__ Bq) {
  const int tid = threadIdx.x;
  const int lane = tid & 63;
  const int strip = tid >> 6;                    // 0..3, 12 h-rows each
  const int d = blockIdx.x;                      // 0..47
  const int ig = blockIdx.y;                     // 0..7
  const float* xb = x + (size_t)blockIdx.z * 32 * V3;
  ushort_t* Bqb = Bq + (size_t)blockIdx.z * ((size_t)1152 * PLANE * 8);

  const int h0 = strip * 12;
  const int gw = lane - 2;
  const bool okw = (gw >= 0 && gw < 48);
  const int sl1 = lane > 0 ? lane - 1 : 0;
  const int sl2 = lane > 1 ? lane - 2 : 0;
  const int sr1 = lane < 63 ? lane + 1 : 63;
  const int sr2 = lane < 62 ? lane + 2 : 63;
  const bool okst = (lane >= 2 && lane <= 49);

  const float* px[4];
#pragma unroll
  for (int ii = 0; ii < 4; ++ii)
    px[ii] = xb + ((size_t)(ig * 4 + ii) * 48 + d) * PLANE + gw;

  float a0[4][5], s1[4][5], s4[4][5];            // rolling 5-row windows

#pragma unroll
  for (int r = 0; r < 16; ++r) {
    const int gh = h0 - 2 + r;
    const bool okv = okw && (gh >= 0) && (gh < 48);
    const int slot = r % 5;
#pragma unroll
    for (int ii = 0; ii < 4; ++ii) {
      float v = okv ? px[ii][gh * 48] : 0.f;
      float vl1 = __shfl(v, sl1);
      float vr1 = __shfl(v, sr1);
      float vl2 = __shfl(v, sl2);
      float vr2 = __shfl(v, sr2);
      a0[ii][slot] = v;                          // dx^2 = 0
      s1[ii][slot] = vl1 + vr1;                  // dx^2 = 1
      s4[ii][slot] = vl2 + vr2;                  // dx^2 = 4
    }
    if (r >= 4) {
      const int j0 = (r - 4) % 5, j1 = (r - 3) % 5, j2 = (r - 2) % 5,
                j3 = (r - 1) % 5, j4 = r % 5;    // j = dy offset 0..4
      uint32_t dw[12];
#pragma unroll
      for (int ii = 0; ii < 4; ++ii) {
        float B0 = a0[ii][j2];
        float B1 = s1[ii][j2] + a0[ii][j1] + a0[ii][j3];
        float B2 = s1[ii][j1] + s1[ii][j3];
        float B3 = s4[ii][j2] + a0[ii][j0] + a0[ii][j4];
        float B4 = s4[ii][j1] + s4[ii][j3] + s1[ii][j0] + s1[ii][j4];
        float B5 = s4[ii][j0] + s4[ii][j4];
        dw[ii * 3 + 0] = pack2(B0, B1);
        dw[ii * 3 + 1] = pack2(B2, B3);
        dw[ii * 3 + 2] = pack2(B4, B5);
      }
      if (okst) {
        const int n = (h0 + r - 4) * 48 + gw;
        const size_t gb = (size_t)(d * 24 + ig * 3);
        uint4 c0 = {dw[0], dw[1], dw[2], dw[3]};
        uint4 c1 = {dw[4], dw[5], dw[6], dw[7]};
        uint4 c2 = {dw[8], dw[9], dw[10], dw[11]};
        *(uint4*)(Bqb + ((gb + 0) * PLANE + n) * 8) = c0;
        *(uint4*)(Bqb + ((gb + 1) * PLANE + n) * 8) = c1;
        *(uint4*)(Bqb + ((gb + 2) * PLANE + n) * 8) = c2;
      }
    }
  }
}

// ---------- pass 2: plane-major GEMM, K = 960 linear walk, ping-pong frags ----------
// out[m][d,n] = sum_kk Afr[kk][m] * Bq[(d-2)*24 + kk/8][n][kk%8] + bias[m]
__global__ __launch_bounds__(256) void gemm_kernel(const ushort_t* __restrict__ Bq,
                                                   const ushort_t* __restrict__ Afr,
                                                   const float* __restrict__ bias,
                                                   float* __restrict__ out) {
  const int tid = threadIdx.x;
  const int lane = tid & 63, wi = tid >> 6;
  const int quad = lane >> 4, m15 = lane & 15;
  const int d = blockIdx.y;
  const ushort_t* Bqb = Bq + (size_t)blockIdx.z * ((size_t)1152 * PLANE * 8);
  float* outb = out + (size_t)blockIdx.z * (size_t)NO * V3;
  const int n0 = blockIdx.x * 128 + wi * 32;

  const int lo = (d < 2) ? (2 - d) : 0;          // dzi range [lo,hi]
  const int hi = (d > 45) ? (49 - d) : 4;
  const int kslo = 6 * lo;
  const int T = 6 * (hi - lo + 1);               // trips: 18/24/30, always even

  const ushort_t* ap = Afr + ((size_t)(kslo * 4 + quad) * 64 + m15) * 8;
  const ushort_t* bp = Bqb + ((size_t)((d - 2) * 24 + kslo * 4 + quad) * PLANE + n0 + m15) * 8;
  const int astep = 4 * 64 * 8;                  // shorts per ks
  const int bstep = 4 * PLANE * 8;

  float4v acc[4][2];
#pragma unroll
  for (int mt = 0; mt < 4; ++mt)
#pragma unroll
    for (int nt = 0; nt < 2; ++nt) acc[mt][nt] = (float4v){0.f, 0.f, 0.f, 0.f};

  short8v A0[4], B0[2], A1[4], B1[2];

#define LOADSET(Ax, Bx)                                                        \
  {                                                                            \
    _Pragma("unroll") for (int mt = 0; mt < 4; ++mt)                           \
        Ax[mt] = *(const short8v*)(ap + mt * 128);                             \
    _Pragma("unroll") for (int nt = 0; nt < 2; ++nt)                           \
        Bx[nt] = *(const short8v*)(bp + nt * 128);                             \
    ap += astep; bp += bstep;                                                  \
  }
#define MFMASET(Ax, Bx)                                                        \
  {                                                                            \
    _Pragma("unroll") for (int mt = 0; mt < 4; ++mt)                           \
        _Pragma("unroll") for (int nt = 0; nt < 2; ++nt)                       \
            acc[mt][nt] = __builtin_amdgcn_mfma_f32_16x16x32_bf16(             \
                Ax[mt], Bx[nt], acc[mt][nt], 0, 0, 0);                         \
  }

  LOADSET(A0, B0);
  for (int k = 1; k + 1 < T; k += 2) {
    LOADSET(A1, B1);
    MFMASET(A0, B0);
    LOADSET(A0, B0);
    MFMASET(A1, B1);
  }
  LOADSET(A1, B1);
  MFMASET(A0, B0);
  MFMASET(A1, B1);
#undef LOADSET
#undef MFMASET

  // C/D: col(n) = lane&15, row(m) = quad*4 + reg
  const int vb = d * PLANE + n0 + m15;
#pragma unroll
  for (int mt = 0; mt < 4; ++mt) {
#pragma unroll
    for (int r = 0; r < 4; ++r) {
      int m = mt * 16 + quad * 4 + r;
      float bv = bias[m];
      float* op = outb + (size_t)m * V3 + vb;
#pragma unroll
      for (int nt = 0; nt < 2; ++nt)
        op[nt * 16] = acc[mt][nt][r] + bv;
    }
  }
}

extern "C" void kernel_launch(void* const* d_in, const int* in_sizes, int n_in,
                              void* d_out, int out_size, void* d_ws, size_t ws_size,
                              hipStream_t stream) {
  const float* x    = (const float*)d_in[0];   // [2,32,1,48,48,48]
  const float* w    = (const float*)d_in[1];   // [64,32,1,1,1,10]
  const float* bias = (const float*)d_in[2];   // [64]
  float* out = (float*)d_out;                  // [2,64,1,48,48,48]

  ushort_t* Afr = (ushort_t*)d_ws;                         // 122880 B
  ushort_t* Bq  = (ushort_t*)((char*)d_ws + 131072);
  const size_t SB = (size_t)1152 * PLANE * 8 * 2;          // 42.5 MB per batch
  const bool both = (ws_size >= 131072 + 2 * SB);

  prep_kernel<<<240, 256, 0, stream>>>(w, Afr);
  if (both) {
    bq_kernel<<<dim3(48, 8, 2), 256, 0, stream>>>(x, Bq);
    gemm_kernel<<<dim3(18, 48, 2), 256, 0, stream>>>(Bq, Afr, bias, out);
  } else {
    for (int b = 0; b < 2; ++b) {
      bq_kernel<<<dim3(48, 8, 1), 256, 0, stream>>>(x + (size_t)b * 32 * V3, Bq);
      gemm_kernel<<<dim3(18, 48, 1), 256, 0, stream>>>(Bq, Afr, bias,
                                                       out + (size_t)b * NO * V3);
    }
  }
}